// Round 4
// baseline (23.242 us; speedup 1.0000x reference)
//
#include <hip/hip_runtime.h>

typedef float f32x4 __attribute__((ext_vector_type(4)));

#define B_ 8
#define N_ 256
#define D_ 128

// ---------------------------------------------------------------------------
// K1: A[r][f] = sum_d x[r][d]*W[d][f] + bias[f];  C[r][f] = sum_d x[r][d]*W[D+d][f]
// grid 256 x block 512. 8 rows/block, one row per wave; fq=tid&63 spans the
// 256 concat cols (float4 each). All 8 waves stream the same 128 KB W panel
// -> L1 reuse; 32 MB total L2 traffic. x tile staged in LDS (wave-uniform reads).
// Vector f32x4 ops let LLVM emit v_pk_fma_f32 / v_pk_add_f32.
// ---------------------------------------------------------------------------
__global__ __launch_bounds__(512) void gemm_ac_kernel(
    const float* __restrict__ x, const float* __restrict__ W,
    const float* __restrict__ bias, float* __restrict__ A, float* __restrict__ C) {
    __shared__ f32x4 xs[8][32];   // 4 KB

    const int tid = threadIdx.x;
    const int r0  = blockIdx.x * 8;
    if (tid < 256) {
        const int row = tid >> 5, dq = tid & 31;
        xs[row][dq] = *reinterpret_cast<const f32x4*>(
            x + (size_t)(r0 + row) * D_ + dq * 4);
    }
    __syncthreads();

    const int r   = tid >> 6;       // 0..7 (wave id -> row)
    const int fq  = tid & 63;       // concat col group (x4)
    const int isC = fq >> 5;
    const int col = (fq & 31) * 4;
    const f32x4* __restrict__ Wv =
        reinterpret_cast<const f32x4*>(W + (isC ? D_ * D_ : 0) + col);
    // row stride of Wv = 32 f32x4

    f32x4 acc = {0.f, 0.f, 0.f, 0.f};
    #pragma unroll 4
    for (int c = 0; c < 32; ++c) {
        const f32x4 xv = xs[r][c];            // wave-uniform broadcast
        acc += xv.x * Wv[(size_t)(c * 4 + 0) * 32];
        acc += xv.y * Wv[(size_t)(c * 4 + 1) * 32];
        acc += xv.z * Wv[(size_t)(c * 4 + 2) * 32];
        acc += xv.w * Wv[(size_t)(c * 4 + 3) * 32];
    }

    const int row = r0 + r;
    if (isC) {
        *reinterpret_cast<f32x4*>(C + (size_t)row * D_ + col) = acc;
    } else {
        acc += *reinterpret_cast<const f32x4*>(bias + col);
        *reinterpret_cast<f32x4*>(A + (size_t)row * D_ + col) = acc;
    }
}

// ---------------------------------------------------------------------------
// K2: out[b,i,f] = sum_j relu(A'[b,i,f] + C[b,j,f])   (bias folded into A)
// grid 512 x block 256: block = (batch b, 4 rows i0..i0+3).
// tid = (jg 0..7) x (fq 0..31). Thread registers-blocks 4 rows so each C
// float4 load feeds 4x relu-adds; C panel read exactly once per block
// (64 MB L2 chip-wide). One LDS exchange over the 8 j-groups at the end.
// ---------------------------------------------------------------------------
__global__ __launch_bounds__(256) void reduce_edges_kernel(
    const float* __restrict__ A, const float* __restrict__ C,
    float* __restrict__ out) {
    __shared__ f32x4 part[8][4][32];   // 16 KB

    const int blk = blockIdx.x;        // 0..511
    const int b   = blk >> 6;
    const int i0  = (blk & 63) * 4;
    const int tid = threadIdx.x;
    const int fq  = tid & 31;
    const int jg  = tid >> 5;          // 0..7

    f32x4 av[4], acc[4];
    const f32x4 zero = {0.f, 0.f, 0.f, 0.f};
    #pragma unroll
    for (int r = 0; r < 4; ++r) {
        av[r] = *reinterpret_cast<const f32x4*>(
            A + ((size_t)(b * N_ + i0 + r)) * D_ + fq * 4);
        acc[r] = zero;
    }

    const f32x4* __restrict__ Cv =
        reinterpret_cast<const f32x4*>(C + (size_t)b * N_ * D_) +
        (size_t)(jg * 32) * 32 + fq;
    #pragma unroll 4
    for (int j = 0; j < 32; ++j) {
        const f32x4 cv = Cv[(size_t)j * 32];
        #pragma unroll
        for (int r = 0; r < 4; ++r) {
            f32x4 t = av[r] + cv;                       // v_pk_add_f32
            t = __builtin_elementwise_max(t, zero);     // relu
            acc[r] += t;                                // v_pk_add_f32
        }
    }

    #pragma unroll
    for (int r = 0; r < 4; ++r) part[jg][r][fq] = acc[r];
    __syncthreads();

    if (tid < 128) {
        const int rr = tid >> 5, ff = tid & 31;
        f32x4 s = part[0][rr][ff];
        #pragma unroll
        for (int k = 1; k < 8; ++k) s += part[k][rr][ff];
        *reinterpret_cast<f32x4*>(
            out + ((size_t)(b * N_ + i0 + rr)) * D_ + ff * 4) = s;
    }
}

// Fallback (only if workspace too small): fully fused, recomputes C per row.
__global__ __launch_bounds__(128) void fused_naive_kernel(
    const float* __restrict__ x, const float* __restrict__ W,
    const float* __restrict__ bias, float* __restrict__ out) {
    const int r = blockIdx.x;
    const int b = r / N_;
    const int f = threadIdx.x;
    const float* __restrict__ xi = x + (size_t)r * D_;
    float a = bias[f];
    for (int d = 0; d < D_; ++d) a += xi[d] * W[d * D_ + f];
    float acc = 0.0f;
    const float* __restrict__ xb = x + (size_t)b * N_ * D_;
    for (int j = 0; j < N_; ++j) {
        const float* __restrict__ xj = xb + (size_t)j * D_;
        float c = 0.0f;
        for (int d = 0; d < D_; ++d) c += xj[d] * W[(D_ + d) * D_ + f];
        acc += fmaxf(a + c, 0.0f);
    }
    out[(size_t)r * D_ + f] = acc;
}

extern "C" void kernel_launch(void* const* d_in, const int* in_sizes, int n_in,
                              void* d_out, int out_size, void* d_ws, size_t ws_size,
                              hipStream_t stream) {
    const float* x    = (const float*)d_in[0];   // (B, N, D) fp32
    const float* W    = (const float*)d_in[1];   // (2D, D)   fp32
    const float* bias = (const float*)d_in[2];   // (D,)      fp32
    float* out = (float*)d_out;                  // (B, N, D) fp32

    const size_t elems = (size_t)B_ * N_ * D_;
    const size_t need  = 2 * elems * sizeof(float);

    if (ws_size >= need) {
        float* A = (float*)d_ws;
        float* C = A + elems;
        gemm_ac_kernel<<<(B_ * N_) / 8, 512, 0, stream>>>(x, W, bias, A, C);
        reduce_edges_kernel<<<(B_ * N_) / 4, 256, 0, stream>>>(A, C, out);
    } else {
        fused_naive_kernel<<<B_ * N_, D_, 0, stream>>>(x, W, bias, out);
    }
}